// Round 1
// baseline (688.724 us; speedup 1.0000x reference)
//
#include <hip/hip_runtime.h>
#include <math.h>

// Problem constants
// x: (16, 64, 256, 256) f32 ; wr/wi: (64, 64, 32, 32) f32 ; out: (16, 64, 256, 256) f32
// Pipeline: F1 (DFT-w, 32 modes) -> F2 (DFT-h, 32 modes) -> M (channel mix) ->
//           I1 (iDFT-h) -> I2 (iDFT-w, real out).
//
// Workspace layout (float offsets):
//   e1 : [256][64]        @ 0        (cos/256, -sin/256 interleaved per ky)
//   tt : [32][256] float2 @ 16384    (cos, sin)
//   e2 : [64][256]        @ 32768    (row 2ky: c*cos, row 2ky+1: -c*sin, c=(ky?2:1)/256)
//   y  : float2[16][64][256][32] @ 65536          (16,777,216 floats)
//   xf : float2[16][64][32][32]  @ 16,842,752     ( 2,097,152 floats)
//   om : float2[16][64][32][32]  @ 18,939,904     ( 2,097,152 floats)
//   g  : aliases y (y dead after F2)
// Total ws: 84,148,224 bytes.

__global__ __launch_bounds__(256) void k_tables(float* __restrict__ ws) {
    int idx = blockIdx.x * 256 + threadIdx.x;   // 0..8191
    const float STEP = 6.283185307179586f / 256.f;
    float s, c;
    {   // E1[w][64]: cols 2ky = cos/256, 2ky+1 = -sin/256
        int w = idx >> 5, ky = idx & 31;
        int t = (w * ky) & 255;
        sincosf((float)t * STEP, &s, &c);
        ws[w * 64 + 2 * ky]     = c * (1.f / 256.f);
        ws[w * 64 + 2 * ky + 1] = -s * (1.f / 256.f);
    }
    {   // tt[kx][h] = (cos, sin) of 2*pi*kx*h/256
        int kx = idx >> 8, h = idx & 255;
        int t = (kx * h) & 255;
        sincosf((float)t * STEP, &s, &c);
        ((float2*)(ws + 16384))[kx * 256 + h] = make_float2(c, s);
    }
    {   // E2: row 2ky = c*cos, row 2ky+1 = -c*sin ; c = (ky==0?1:2)/256
        int ky = idx >> 8, w = idx & 255;
        int t = (ky * w) & 255;
        sincosf((float)t * STEP, &s, &c);
        float cc = (ky == 0 ? 1.f : 2.f) / 256.f;
        ws[32768 + (2 * ky) * 256 + w]     = cc * c;
        ws[32768 + (2 * ky + 1) * 256 + w] = -cc * s;
    }
}

// K1: Y[M=262144][64] = X[M][256] * E1[256][64].  BM=128, BN=64, BK=32.
__global__ __launch_bounds__(256) void k_f1(const float* __restrict__ x,
                                            const float* __restrict__ e1,
                                            float* __restrict__ y) {
    __shared__ float As[32 * 132];   // k-major [k][row], pad 132
    __shared__ float Bs[32 * 64];    // [k][n]
    int t = threadIdx.x, tx = t & 15, ty = t >> 4;
    int row0 = blockIdx.x * 128;
    float acc[8][4];
#pragma unroll
    for (int i = 0; i < 8; ++i)
#pragma unroll
        for (int j = 0; j < 4; ++j) acc[i][j] = 0.f;

    for (int kt = 0; kt < 8; ++kt) {
        // stage A: 128 rows x 32 k (transpose to k-major)
#pragma unroll
        for (int n = 0; n < 4; ++n) {
            int f4 = t + n * 256;
            int r = f4 >> 3, c4 = f4 & 7;
            float4 v = *(const float4*)&x[(long)(row0 + r) * 256 + kt * 32 + c4 * 4];
            As[(c4 * 4 + 0) * 132 + r] = v.x;
            As[(c4 * 4 + 1) * 132 + r] = v.y;
            As[(c4 * 4 + 2) * 132 + r] = v.z;
            As[(c4 * 4 + 3) * 132 + r] = v.w;
        }
        // stage B: 32 k x 64 n
#pragma unroll
        for (int n = 0; n < 2; ++n) {
            int f4 = t + n * 256;
            int k = f4 >> 4, c4 = f4 & 15;
            *(float4*)&Bs[k * 64 + c4 * 4] = *(const float4*)&e1[(kt * 32 + k) * 64 + c4 * 4];
        }
        __syncthreads();
#pragma unroll
        for (int k = 0; k < 32; ++k) {
            float4 a0 = *(const float4*)&As[k * 132 + ty * 4];
            float4 a1 = *(const float4*)&As[k * 132 + 64 + ty * 4];
            float4 b0 = *(const float4*)&Bs[k * 64 + tx * 4];
            float av[8] = {a0.x, a0.y, a0.z, a0.w, a1.x, a1.y, a1.z, a1.w};
            float bv[4] = {b0.x, b0.y, b0.z, b0.w};
#pragma unroll
            for (int i = 0; i < 8; ++i)
#pragma unroll
                for (int j = 0; j < 4; ++j)
                    acc[i][j] = fmaf(av[i], bv[j], acc[i][j]);
        }
        __syncthreads();
    }
#pragma unroll
    for (int i = 0; i < 8; ++i) {
        int r = row0 + ((i < 4) ? (ty * 4 + i) : (64 + ty * 4 + i - 4));
        float4 v = make_float4(acc[i][0], acc[i][1], acc[i][2], acc[i][3]);
        *(float4*)&y[(long)r * 64 + tx * 4] = v;
    }
}

// K2: per batch (b,i): C[64][64] = [Tc;Ts](64x256) * Y(256x64-interleaved)
//     xf_re = C[kx][2ky] + C[kx+32][2ky+1]; xf_im = C[kx][2ky+1] - C[kx+32][2ky]
__global__ __launch_bounds__(256) void k_f2(const float2* __restrict__ tt,
                                            const float2* __restrict__ y,
                                            float2* __restrict__ xf) {
    __shared__ float smem[2176 + 2048];  // As[32][68] + Bs[32][64]; reused as Cs[64][65]
    float* As = smem;
    float* Bs = smem + 2176;
    int t = threadIdx.x, tx = t & 15, ty = t >> 4;
    int batch = blockIdx.x;
    const float2* ybase = y + (long)batch * 256 * 32;
    float acc[4][4];
#pragma unroll
    for (int i = 0; i < 4; ++i)
#pragma unroll
        for (int j = 0; j < 4; ++j) acc[i][j] = 0.f;

    for (int ht = 0; ht < 8; ++ht) {
        int h0 = ht * 32;
#pragma unroll
        for (int n = 0; n < 4; ++n) {     // A: 32 kx x 32 h (cos->m=kx, sin->m=kx+32)
            int i2 = t + n * 256;
            int kx = i2 >> 5, hh = i2 & 31;
            float2 cs = tt[kx * 256 + h0 + hh];
            As[hh * 68 + kx] = cs.x;
            As[hh * 68 + 32 + kx] = cs.y;
        }
#pragma unroll
        for (int n = 0; n < 4; ++n) {     // B: 32 h x 32 ky (float2)
            int i2 = t + n * 256;
            int hh = i2 >> 5, ky = i2 & 31;
            float2 v = ybase[(h0 + hh) * 32 + ky];
            *(float2*)&Bs[hh * 64 + 2 * ky] = v;
        }
        __syncthreads();
#pragma unroll
        for (int kk = 0; kk < 32; ++kk) {
            float4 a0 = *(const float4*)&As[kk * 68 + ty * 4];
            float4 b0 = *(const float4*)&Bs[kk * 64 + tx * 4];
            float av[4] = {a0.x, a0.y, a0.z, a0.w};
            float bv[4] = {b0.x, b0.y, b0.z, b0.w};
#pragma unroll
            for (int i = 0; i < 4; ++i)
#pragma unroll
                for (int j = 0; j < 4; ++j)
                    acc[i][j] = fmaf(av[i], bv[j], acc[i][j]);
        }
        __syncthreads();
    }
    // write C into LDS, combine, output
    float* Cs = smem;   // 64*65 = 4160 <= 4224
#pragma unroll
    for (int i = 0; i < 4; ++i)
#pragma unroll
        for (int j = 0; j < 4; ++j)
            Cs[(ty * 4 + i) * 65 + tx * 4 + j] = acc[i][j];
    __syncthreads();
#pragma unroll
    for (int n = 0; n < 4; ++n) {
        int idx = t + n * 256;
        int kx = idx >> 5, ky = idx & 31;
        float re = Cs[kx * 65 + 2 * ky]     + Cs[(kx + 32) * 65 + 2 * ky + 1];
        float im = Cs[kx * 65 + 2 * ky + 1] - Cs[(kx + 32) * 65 + 2 * ky];
        xf[(long)batch * 1024 + kx * 32 + ky] = make_float2(re, im);
    }
}

// K3: per (b,kx): om[b,o,kx,ky] = sum_i xf[b,i,kx,ky] * (wr+i*wi)[i,o,kx,ky]
__global__ __launch_bounds__(256) void k_mix(const float* __restrict__ wr,
                                             const float* __restrict__ wi,
                                             const float2* __restrict__ xf,
                                             float2* __restrict__ om) {
    __shared__ float2 xs[64 * 32];   // [i][ky]
    int t = threadIdx.x;
    int b = blockIdx.x >> 5, kx = blockIdx.x & 31;
#pragma unroll
    for (int n = 0; n < 8; ++n) {
        int i2 = t + n * 256;
        int i = i2 >> 5, ky = i2 & 31;
        xs[i2] = xf[(long)(b * 64 + i) * 1024 + kx * 32 + ky];
    }
    __syncthreads();
    int ky = t & 31, og = t >> 5;
    float ar[8], ai[8];
#pragma unroll
    for (int j = 0; j < 8; ++j) { ar[j] = 0.f; ai[j] = 0.f; }
    const float* wrb = wr + kx * 32 + ky;
    const float* wib = wi + kx * 32 + ky;
    for (int i = 0; i < 64; ++i) {
        float2 xv = xs[i * 32 + ky];
#pragma unroll
        for (int j = 0; j < 8; ++j) {
            int o = og * 8 + j;
            long woff = (long)(i * 64 + o) * 1024;
            float wrv = wrb[woff], wiv = wib[woff];
            ar[j] = fmaf(xv.x, wrv, fmaf(-xv.y, wiv, ar[j]));
            ai[j] = fmaf(xv.x, wiv, fmaf(xv.y, wrv, ai[j]));
        }
    }
    float2* omb = om + (long)(b * 64) * 1024 + kx * 32 + ky;
#pragma unroll
    for (int j = 0; j < 8; ++j) {
        int o = og * 8 + j;
        omb[(long)o * 1024] = make_float2(ar[j], ai[j]);
    }
}

// K4: per (b,o) x 4 h-blocks: C[64h][64] = A[64h][64k] * Bm[64k][64]
//     A: k<32 -> cos(2pi k h/256); k>=32 -> sin. Bm built from om with conj-free signs.
__global__ __launch_bounds__(256) void k_i1(const float2* __restrict__ tt,
                                            const float2* __restrict__ om,
                                            float2* __restrict__ g) {
    __shared__ float As[64 * 68];
    __shared__ float Bs[64 * 64];
    int t = threadIdx.x, tx = t & 15, ty = t >> 4;
    int bo = blockIdx.x >> 2, hb = blockIdx.x & 3;
    int h0 = hb * 64;
#pragma unroll
    for (int n = 0; n < 8; ++n) {   // A: 32 kx x 64 h
        int i2 = t + n * 256;
        int kx = i2 >> 6, hh = i2 & 63;
        float2 cs = tt[kx * 256 + h0 + hh];
        As[kx * 68 + hh] = cs.x;
        As[(kx + 32) * 68 + hh] = cs.y;
    }
    const float2* ombase = om + (long)bo * 1024;
#pragma unroll
    for (int n = 0; n < 4; ++n) {   // B from om
        int i2 = t + n * 256;
        int kx = i2 >> 5, ky = i2 & 31;
        float2 v = ombase[kx * 32 + ky];
        Bs[kx * 64 + 2 * ky] = v.x;
        Bs[kx * 64 + 2 * ky + 1] = v.y;
        Bs[(kx + 32) * 64 + 2 * ky] = -v.y;
        Bs[(kx + 32) * 64 + 2 * ky + 1] = v.x;
    }
    __syncthreads();
    float acc[4][4];
#pragma unroll
    for (int i = 0; i < 4; ++i)
#pragma unroll
        for (int j = 0; j < 4; ++j) acc[i][j] = 0.f;
#pragma unroll 16
    for (int k = 0; k < 64; ++k) {
        float4 a0 = *(const float4*)&As[k * 68 + ty * 4];
        float4 b0 = *(const float4*)&Bs[k * 64 + tx * 4];
        float av[4] = {a0.x, a0.y, a0.z, a0.w};
        float bv[4] = {b0.x, b0.y, b0.z, b0.w};
#pragma unroll
        for (int i = 0; i < 4; ++i)
#pragma unroll
            for (int j = 0; j < 4; ++j)
                acc[i][j] = fmaf(av[i], bv[j], acc[i][j]);
    }
    float2* gbase = g + (long)bo * 256 * 32;
#pragma unroll
    for (int i = 0; i < 4; ++i) {
        float4 v = make_float4(acc[i][0], acc[i][1], acc[i][2], acc[i][3]);
        *(float4*)&gbase[(h0 + ty * 4 + i) * 32 + tx * 2] = v;
    }
}

// K5: out[M=262144][256] = G[M][64] * E2[64][256].  BM=64, BN=128, K=64.
__global__ __launch_bounds__(256) void k_i2(const float* __restrict__ g,
                                            const float* __restrict__ e2,
                                            float* __restrict__ out) {
    __shared__ float As[64 * 68];    // k-major [k][row]
    __shared__ float Bs[64 * 128];   // [k][n]
    int t = threadIdx.x, tx = t & 15, ty = t >> 4;
    int rb = blockIdx.x >> 1, wb = blockIdx.x & 1;
    int row0 = rb * 64;
#pragma unroll
    for (int n = 0; n < 4; ++n) {    // A: 64 rows x 64 k (transpose)
        int f4 = t + n * 256;
        int r = f4 >> 4, c4 = f4 & 15;
        float4 v = *(const float4*)&g[(long)(row0 + r) * 64 + c4 * 4];
        As[(c4 * 4 + 0) * 68 + r] = v.x;
        As[(c4 * 4 + 1) * 68 + r] = v.y;
        As[(c4 * 4 + 2) * 68 + r] = v.z;
        As[(c4 * 4 + 3) * 68 + r] = v.w;
    }
#pragma unroll
    for (int n = 0; n < 8; ++n) {    // B: 64 k x 128 w
        int f4 = t + n * 256;
        int k = f4 >> 5, w4 = f4 & 31;
        *(float4*)&Bs[k * 128 + w4 * 4] = *(const float4*)&e2[k * 256 + wb * 128 + w4 * 4];
    }
    __syncthreads();
    float acc[4][8];
#pragma unroll
    for (int i = 0; i < 4; ++i)
#pragma unroll
        for (int j = 0; j < 8; ++j) acc[i][j] = 0.f;
#pragma unroll 16
    for (int k = 0; k < 64; ++k) {
        float4 a0 = *(const float4*)&As[k * 68 + ty * 4];
        float4 b0 = *(const float4*)&Bs[k * 128 + tx * 4];
        float4 b1 = *(const float4*)&Bs[k * 128 + 64 + tx * 4];
        float av[4] = {a0.x, a0.y, a0.z, a0.w};
        float bv[8] = {b0.x, b0.y, b0.z, b0.w, b1.x, b1.y, b1.z, b1.w};
#pragma unroll
        for (int i = 0; i < 4; ++i)
#pragma unroll
            for (int j = 0; j < 8; ++j)
                acc[i][j] = fmaf(av[i], bv[j], acc[i][j]);
    }
#pragma unroll
    for (int i = 0; i < 4; ++i) {
        long ro = (long)(row0 + ty * 4 + i) * 256 + wb * 128;
        float4 v0 = make_float4(acc[i][0], acc[i][1], acc[i][2], acc[i][3]);
        float4 v1 = make_float4(acc[i][4], acc[i][5], acc[i][6], acc[i][7]);
        *(float4*)&out[ro + tx * 4] = v0;
        *(float4*)&out[ro + 64 + tx * 4] = v1;
    }
}

extern "C" void kernel_launch(void* const* d_in, const int* in_sizes, int n_in,
                              void* d_out, int out_size, void* d_ws, size_t ws_size,
                              hipStream_t stream) {
    const float* x  = (const float*)d_in[0];
    const float* wr = (const float*)d_in[1];
    const float* wi = (const float*)d_in[2];
    float* out = (float*)d_out;
    float* ws = (float*)d_ws;

    float*  e1 = ws;                          // 16384 floats
    float2* tt = (float2*)(ws + 16384);       // 8192 float2
    float*  e2 = ws + 32768;                  // 16384 floats
    float*  y  = ws + 65536;                  // 16,777,216 floats (float2 view)
    float*  xf = ws + 65536 + 16777216;       // 2,097,152 floats
    float*  om = ws + 65536 + 16777216 + 2097152;
    float*  g  = y;                           // alias (y dead after k_f2)

    hipLaunchKernelGGL(k_tables, dim3(32),   dim3(256), 0, stream, ws);
    hipLaunchKernelGGL(k_f1,     dim3(2048), dim3(256), 0, stream, x, e1, y);
    hipLaunchKernelGGL(k_f2,     dim3(1024), dim3(256), 0, stream, tt, (const float2*)y, (float2*)xf);
    hipLaunchKernelGGL(k_mix,    dim3(512),  dim3(256), 0, stream, wr, wi, (const float2*)xf, (float2*)om);
    hipLaunchKernelGGL(k_i1,     dim3(4096), dim3(256), 0, stream, tt, (const float2*)om, (float2*)g);
    hipLaunchKernelGGL(k_i2,     dim3(8192), dim3(256), 0, stream, g, e2, out);
}